// Round 9
// baseline (1036.579 us; speedup 1.0000x reference)
//
#include <hip/hip_runtime.h>
#include <hip/hip_bf16.h>

#define NTOK 511
#define NINT 255

typedef unsigned short u16;
typedef __attribute__((ext_vector_type(8))) short bf16x8;
typedef __attribute__((ext_vector_type(4))) float f32x4;

// ---- workspace layout (4-byte offsets) ----
constexpr int OFF_FLAG = 0;                 // [0] dtype flag
constexpr int OFF_WB   = 4;                 // bf16 weight region
// binW: [jc][56 frags]: f0-15 Wx(g=f>>2,ks=f&3); f16-55 Ub(g=(f-16)>>3,ks=(f-16)&7)
// unW:  [jc][16 frags]: Uu(g=f>>2,ks=f&3)
constexpr int BINW = 0;                     // 8*56*512 = 229376 bf16
constexpr int UNW  = 229376;                // 8*16*512 = 65536
constexpr int W3B  = 294912;                // 8*4*512  = 16384
constexpr int WB_ELEMS = 311296;
constexpr int OFF_BIAS = OFF_WB + WB_ELEMS / 2;      // 155652
constexpr int BW4 = 0, BUB4 = 512, BUB1 = 1024, BUU4 = 1152, B3 = 1664;
constexpr int BIAS_FLOATS = 1792;
constexpr int OFF_ROOT = OFF_BIAS + BIAS_FLOATS;     // 157444: rootH 32768 + rootC 32768
constexpr int OFF_CNT  = OFF_ROOT + 65536;           // 222980: cnt[cidx][l][2]   (4096)
constexpr int OFF_POS  = OFF_CNT + 4096;             // pos[cidx][l][2]           (4096)
constexpr int OFF_HDR  = OFF_POS + 4096;             // hdr[cidx][l][4]           (8192)
constexpr int OFF_LIST = OFF_HDR + 8192;             // 239364: node lists        (196608)
constexpr int OFF_CHUNK = OFF_LIST + 196608 + 28;    // 436000 (16B-aligned: *4 %16==0)
constexpr long PER_TREE = 49152;            // floats: Ha bf16 + Hb bf16 + Ca f32 + Cb f32

__device__ __forceinline__ float bf2f(__hip_bfloat16 v) { return __bfloat162float(v); }
__device__ __forceinline__ short f2s(float f) {
    __hip_bfloat16 b = __float2bfloat16(f);
    return *reinterpret_cast<short*>(&b);
}
__device__ __forceinline__ float sigm(float x) { return 1.0f / (1.0f + __expf(-x)); }
__device__ __forceinline__ float tanh_(float x) { return 1.0f - 2.0f / (__expf(2.0f * x) + 1.0f); }

__device__ __forceinline__ float ldf(const void* p, long idx, int isbf) {
    return isbf ? bf2f(((const __hip_bfloat16*)p)[idx]) : ((const float*)p)[idx];
}

__device__ __forceinline__ bf16x8 ldA(const void* p, long idx, int isbf) {
    if (isbf) return *(const bf16x8*)((const short*)p + idx);
    const float* f = (const float*)p + idx;
    float4 a = *(const float4*)f, b = *(const float4*)(f + 4);
    bf16x8 r;
    r[0] = f2s(a.x); r[1] = f2s(a.y); r[2] = f2s(a.z); r[3] = f2s(a.w);
    r[4] = f2s(b.x); r[5] = f2s(b.y); r[6] = f2s(b.z); r[7] = f2s(b.w);
    return r;
}

// async global->LDS 16B
typedef const __attribute__((address_space(1))) unsigned int* gp1_t;
typedef __attribute__((address_space(3))) unsigned int* lp3_t;
__device__ __forceinline__ void stage16(const void* g, void* l) {
    __builtin_amdgcn_global_load_lds((gp1_t)g, (lp3_t)l, 16, 0, 0);
}
// stage F frags (F multiple of 4): F*1024 bytes with 256 threads x 16B
__device__ __forceinline__ void stageF(const short* g, short* l, int t, int frags) {
    int iters = frags >> 2;
    for (int s = 0; s < iters; ++s) {
        int off = (s * 256 + t) * 8;
        stage16(g + off, l + off);
    }
}

// ---- dtype detection ----
__global__ void detect_kernel(const void* W, float* ws) {
    if (threadIdx.x == 0 && blockIdx.x == 0) {
        const u16* u = (const u16*)W;
        int cnt = 0;
        for (int i = 0; i < 128; i += 2) {
            u16 x = u[i];
            int ex = (x >> 7) & 0xff;
            if (x == 0 || (ex >= 96 && ex <= 127)) cnt++;
        }
        ((int*)ws)[0] = (cnt >= 48) ? 1 : 0;
    }
}

// ---- repack: raw weights -> type-split bf16 frag-linear + fp32 biases ----
__global__ __launch_bounds__(256) void repack_mfma(
    const void* W, const void* bW, const void* Ubin, const void* bUbin,
    const void* Uun, const void* bUun, float* ws)
{
    const int isbf = ((const int*)ws)[0];
    short* wb = (short*)(ws + OFF_WB);
    float* bias = ws + OFF_BIAS;
    int tid = blockIdx.x * blockDim.x + threadIdx.x;
    int nth = gridDim.x * blockDim.x;

    // binW
    for (int idx = tid; idx < 229376; idx += nth) {
        int e = idx & 511, fjc = idx >> 9;
        int jc = fjc / 56, f = fjc - jc * 56;
        int lane = e >> 3, id8 = e & 7;
        int j = jc * 16 + (lane & 15);
        float v;
        if (f < 16) {
            int g = f >> 2, ks = f & 3;
            int k = ks * 32 + (lane >> 4) * 8 + id8;
            v = ldf(W, (long)g * 16384 + k * 128 + j, isbf);
        } else {
            int fb = f - 16; int g = fb >> 3, ks = fb & 7;
            int k = ks * 32 + (lane >> 4) * 8 + id8;
            v = ldf(Ubin, (long)g * 32768 + k * 128 + j, isbf);
        }
        wb[BINW + idx] = f2s(v);
    }
    // unW
    for (int idx = tid; idx < 65536; idx += nth) {
        int e = idx & 511, fjc = idx >> 9;
        int jc = fjc >> 4, f = fjc & 15;
        int lane = e >> 3, id8 = e & 7;
        int g = f >> 2, ks = f & 3;
        int k = ks * 32 + (lane >> 4) * 8 + id8;
        int j = jc * 16 + (lane & 15);
        wb[UNW + idx] = f2s(ldf(Uun, (long)g * 16384 + k * 128 + j, isbf));
    }
    // W3
    for (int idx = tid; idx < 16384; idx += nth) {
        int e = idx & 511, frag = idx >> 9;
        int jc = frag >> 2, ks = frag & 3;
        int lane = e >> 3, id8 = e & 7;
        int k = ks * 32 + (lane >> 4) * 8 + id8;
        int j = jc * 16 + (lane & 15);
        wb[W3B + idx] = f2s(ldf(W, (long)3 * 16384 + k * 128 + j, isbf));
    }
    for (int j = tid; j < 128; j += nth) {
        float4 b;
        b.x = ldf(bW, 0 * 128 + j, isbf); b.y = ldf(bW, 1 * 128 + j, isbf);
        b.z = ldf(bW, 2 * 128 + j, isbf); b.w = ldf(bW, 3 * 128 + j, isbf);
        ((float4*)(bias + BW4))[j] = b;
        float4 bb;
        bb.x = ldf(bUbin, 0 * 128 + j, isbf); bb.y = ldf(bUbin, 1 * 128 + j, isbf);
        bb.z = ldf(bUbin, 2 * 128 + j, isbf); bb.w = ldf(bUbin, 3 * 128 + j, isbf);
        ((float4*)(bias + BUB4))[j] = bb;
        (bias + BUB1)[j] = ldf(bUbin, 4 * 128 + j, isbf);
        float4 bu;
        bu.x = ldf(bUun, 0 * 128 + j, isbf); bu.y = ldf(bUun, 1 * 128 + j, isbf);
        bu.z = ldf(bUun, 2 * 128 + j, isbf); bu.w = ldf(bUun, 3 * 128 + j, isbf);
        ((float4*)(bias + BUU4))[j] = bu;
        (bias + B3)[j] = ldf(bW, 3 * 128 + j, isbf);
    }
}

// ---- prepass: arity-partitioned node lists per (chunk, level) ----
__global__ __launch_bounds__(256) void count_kernel(const int* __restrict__ arity,
                                                    int* ws_i, int bcsh)
{
    int b = blockIdx.x, i = threadIdx.x;
    if (i >= 255) return;
    int l = 31 - __clz(i + 1);
    int type = (arity[b * NINT + i] == 1) ? 0 : 1;
    int cidx = b >> bcsh;
    atomicAdd(ws_i + OFF_CNT + (cidx * 8 + l) * 2 + type, 1);
}

__global__ void hdr_kernel(int* ws_i, int nPairs)
{
    for (int idx = threadIdx.x; idx < nPairs; idx += 256) {
        int nbin = ws_i[OFF_CNT + idx * 2], nun = ws_i[OFF_CNT + idx * 2 + 1];
        int B16 = (nbin + 15) & ~15;
        int T = B16 + ((nun + 15) & ~15);
        int* h = ws_i + OFF_HDR + idx * 4;
        h[0] = nbin; h[1] = B16; h[2] = T; h[3] = nun;
    }
}

__global__ __launch_bounds__(256) void scatter_kernel(const int* __restrict__ arity,
                                                      int* ws_i, int bcsh, int Bc, int lstride)
{
    int b = blockIdx.x, i = threadIdx.x;
    if (i >= 255) return;
    int l = 31 - __clz(i + 1);
    int o2 = (1 << l) - 1;
    int iin = i - o2;
    int type = (arity[b * NINT + i] == 1) ? 0 : 1;
    int cidx = b >> bcsh;
    int localb = b - (cidx << bcsh);
    int pairIdx = cidx * 8 + l;
    int pos = atomicAdd(ws_i + OFF_POS + pairIdx * 2 + type, 1);
    int slot = (type == 0) ? pos : ws_i[OFF_HDR + pairIdx * 4 + 1] + pos;
    int lbase = cidx * lstride + Bc * o2 + 64 * l;
    ws_i[OFF_LIST + lbase + slot] = (localb << l) | iin;
}

__global__ void pad_kernel(int* ws_i, int nPairs, int Bc, int lstride)
{
    for (int idx = threadIdx.x; idx < nPairs; idx += 256) {
        int cidx = idx >> 3, l = idx & 7;
        int* h = ws_i + OFF_HDR + idx * 4;
        int nbin = h[0], B16 = h[1], T = h[2], nun = h[3];
        int lbase = cidx * lstride + Bc * ((1 << l) - 1) + 64 * l;
        int* lst = ws_i + OFF_LIST + lbase;
        if (nbin > 0) for (int s = nbin; s < B16; ++s) lst[s] = lst[0];
        if (nun > 0)  for (int s = B16 + nun; s < T; ++s) lst[s] = lst[B16];
    }
}

#define MFMA(A, B, C) __builtin_amdgcn_mfma_f32_16x16x32_bf16(A, B, C, 0, 0, 0)

// ---- leaf: h = tanh(x @ W3 + b3); W3 in registers, no barriers ----
__global__ __launch_bounds__(256, 2) void leaf_mfma(
    const int* __restrict__ tokens, const void* emb, const float* __restrict__ ws,
    short* __restrict__ hOut, int treeOff, int Mtot, int iters)
{
    __shared__ short hst[4][16][132];
    const int t = threadIdx.x;
    const int isbf = ((const int*)ws)[0];
    const int wv = t >> 6, lane = t & 63, quad = lane >> 4, l16 = lane & 15;
    const short* wb = (const short*)(ws + OFF_WB);
    const float* bias = ws + OFF_BIAS;

    bf16x8 bf[32];
#pragma unroll
    for (int f = 0; f < 32; ++f)
        bf[f] = *(const bf16x8*)(wb + W3B + f * 512 + lane * 8);
    float b3v[8];
#pragma unroll
    for (int jc = 0; jc < 8; ++jc) b3v[jc] = (bias + B3)[jc * 16 + l16];

    for (int it = 0; it < iters; ++it) {
        int rb = (blockIdx.x * iters + it) * 64 + wv * 16;
        if (rb >= Mtot) break;
        int p = rb + l16; if (p >= Mtot) p = Mtot - 1;
        int bl = p >> 8, i = p & 255;
        int tk = tokens[(long)(treeOff + bl) * NTOK + 255 + i];
        bf16x8 ax[4];
#pragma unroll
        for (int ks = 0; ks < 4; ++ks)
            ax[ks] = ldA(emb, (long)tk * 128 + ks * 32 + quad * 8, isbf);
        f32x4 acc[8];
#pragma unroll
        for (int jc = 0; jc < 8; ++jc) acc[jc] = {0.f, 0.f, 0.f, 0.f};
#pragma unroll
        for (int jc = 0; jc < 8; ++jc)
#pragma unroll
            for (int ks = 0; ks < 4; ++ks)
                acc[jc] = MFMA(ax[ks], bf[jc * 4 + ks], acc[jc]);
#pragma unroll
        for (int jc = 0; jc < 8; ++jc)
#pragma unroll
            for (int r = 0; r < 4; ++r)
                hst[wv][quad * 4 + r][jc * 16 + l16] = f2s(tanh_(acc[jc][r] + b3v[jc]));
        int nloc = lane >> 2, c0 = (lane & 3) * 4;
        int prow = rb + nloc;
        if (prow < Mtot) {
#pragma unroll
            for (int jcb = 0; jcb < 8; ++jcb) {
                uint2 v = *(const uint2*)&hst[wv][nloc][jcb * 16 + c0];
                *(uint2*)&hOut[((long)jcb * Mtot + prow) * 16 + c0] = v;
            }
        }
    }
}

// ---- internal level: arity-sorted 64-node blocks, type-pure 16-node subtiles ----
template <int JCC>
__global__ __launch_bounds__(256, 3) void level_mfma(
    const int* __restrict__ tokens, const void* emb,
    const float* __restrict__ ws, const short* __restrict__ hChild,
    const float* __restrict__ cChild, short* __restrict__ hOut, float* __restrict__ cOut,
    float* __restrict__ rootH, float* __restrict__ rootC,
    int lvl, int treeOff, int leafchild, int isRoot, int Mtot, int Mchild,
    int NBM, int hdrIdx, int lbase)
{
    __shared__ short Bs[32 * 512];        // 32 KB stage buffer
    __shared__ short hst[4][16][20];      // wave-private h transpose
    __shared__ int nid[64];
    __shared__ int tokL[64];

    const int t = threadIdx.x;
    const int isbf = ((const int*)ws)[0];
    const int jsx = blockIdx.x / NBM, mb = blockIdx.x - jsx * NBM;
    const int jcLo = jsx * JCC;
    const int p0 = mb * 64;
    const int* hdr = (const int*)ws + OFF_HDR + hdrIdx * 4;
    const int B16 = hdr[1], T = hdr[2];
    if (p0 >= T) return;
    const int* list = (const int*)ws + OFF_LIST + lbase;
    const int wv = t >> 6, lane = t & 63, quad = lane >> 4, l16 = lane & 15;
    const int cnt = 1 << lvl, o2 = cnt - 1;
    const short* wb = (const short*)(ws + OFF_WB);
    const float* bias = ws + OFF_BIAS;

    if (t < 64) {
        int pos = p0 + t; if (pos >= T) pos = T - 1;
        int node = list[pos];
        nid[t] = node;
        int bl = node >> lvl, i = node - (bl << lvl);
        tokL[t] = tokens[(long)(treeOff + bl) * NTOK + o2 + i];
    }
    __syncthreads();

    const int sPos = p0 + wv * 16;
    const bool stBin = (sPos < B16);
    const bool alive = (sPos < T);
    const bool hasBin = (p0 < B16);
    const int hiPos = (p0 + 64 < T) ? (p0 + 64) : T;
    const bool hasUn = (hiPos > B16);

    // A-fragments
    bf16x8 ax[4], ah[8];
    {
        int row = wv * 16 + l16;
        int node = nid[row];
        int bl = node >> lvl, i = node - (bl << lvl);
        long crow = (long)bl * (cnt << 1) + 2 * i;
        int tk = tokL[row];
#pragma unroll
        for (int ks = 0; ks < 4; ++ks)
            ax[ks] = ldA(emb, (long)tk * 128 + ks * 32 + quad * 8, isbf);
#pragma unroll
        for (int ks = 0; ks < 8; ++ks) {
            int k0 = ks * 32 + quad * 8;
            int side = k0 >> 7, kl = k0 & 127;
            ah[ks] = *(const bf16x8*)(hChild +
                ((long)(kl >> 4) * Mchild + crow + side) * 16 + (kl & 15));
        }
    }

    for (int jx = 0; jx < JCC; ++jx) {
        const int jc = jcLo + jx;
        const short* wbin = wb + BINW + (long)jc * (56 * 512);
        const short* wun  = wb + UNW  + (long)jc * (16 * 512);
        const int j = jc * 16 + l16;
        const float4 bw = ((const float4*)(bias + BW4))[j];
        const float4 bb = ((const float4*)(bias + BUB4))[j];
        const float  b1 = (bias + BUB1)[j];
        const float4 bu = ((const float4*)(bias + BUU4))[j];

        // c prefetch for this jc
        float clv[4], crv[4];
#pragma unroll
        for (int r = 0; r < 4; ++r) {
            clv[r] = 0.f; crv[r] = 0.f;
            if (!leafchild) {
                int rowe = wv * 16 + quad * 4 + r;
                int node = nid[rowe];
                int bl = node >> lvl, i = node - (bl << lvl);
                long crowe = (long)bl * (cnt << 1) + 2 * i;
                clv[r] = cChild[((long)jc * Mchild + crowe) * 16 + l16];
                if (stBin) crv[r] = cChild[((long)jc * Mchild + crowe + 1) * 16 + l16];
            }
        }

        // bias-folded accumulator init
        f32x4 aW[4], aB[5], aU[4];
        aW[0] = (f32x4){bw.x, bw.x, bw.x, bw.x};
        aW[1] = (f32x4){bw.y, bw.y, bw.y, bw.y};
        aW[2] = (f32x4){bw.z, bw.z, bw.z, bw.z};
        aW[3] = (f32x4){bw.w, bw.w, bw.w, bw.w};
        aB[0] = (f32x4){bb.x, bb.x, bb.x, bb.x};
        aB[1] = (f32x4){bb.y, bb.y, bb.y, bb.y};
        aB[2] = (f32x4){bb.z, bb.z, bb.z, bb.z};
        aB[3] = (f32x4){bb.w, bb.w, bb.w, bb.w};
        aB[4] = (f32x4){b1, b1, b1, b1};
        aU[0] = (f32x4){bu.x, bu.x, bu.x, bu.x};
        aU[1] = (f32x4){bu.y, bu.y, bu.y, bu.y};
        aU[2] = (f32x4){bu.z, bu.z, bu.z, bu.z};
        aU[3] = (f32x4){bu.w, bu.w, bu.w, bu.w};

        if (hasBin) {
            // pass A: Wx(16) + Ub g0,g1(16)
            stageF(wbin, Bs, t, 32);
            __syncthreads();
            if (alive) {
#pragma unroll
                for (int f = 0; f < 16; ++f) {
                    bf16x8 b = *(const bf16x8*)&Bs[f * 512 + lane * 8];
                    aW[f >> 2] = MFMA(ax[f & 3], b, aW[f >> 2]);
                }
            }
            if (stBin) {
#pragma unroll
                for (int f = 16; f < 32; ++f) {
                    bf16x8 b = *(const bf16x8*)&Bs[f * 512 + lane * 8];
                    int fb = f - 16;
                    aB[fb >> 3] = MFMA(ah[fb & 7], b, aB[fb >> 3]);
                }
            }
            __syncthreads();
            // pass B: Ub g2..g4 (24)
            stageF(wbin + 32 * 512, Bs, t, 24);
            __syncthreads();
            if (stBin) {
#pragma unroll
                for (int f = 0; f < 24; ++f) {
                    bf16x8 b = *(const bf16x8*)&Bs[f * 512 + lane * 8];
                    int fb = f + 16;
                    aB[fb >> 3] = MFMA(ah[fb & 7], b, aB[fb >> 3]);
                }
            }
            if (hasUn) {
                __syncthreads();
                stageF(wun, Bs, t, 16);
                __syncthreads();
                if (alive && !stBin) {
#pragma unroll
                    for (int f = 0; f < 16; ++f) {
                        bf16x8 b = *(const bf16x8*)&Bs[f * 512 + lane * 8];
                        aU[f >> 2] = MFMA(ah[f & 3], b, aU[f >> 2]);
                    }
                }
            }
        } else {
            // pure un block: Wx + Uu in one pass
            stageF(wbin, Bs, t, 16);
            stageF(wun, Bs + 16 * 512, t, 16);
            __syncthreads();
            if (alive) {
#pragma unroll
                for (int f = 0; f < 16; ++f) {
                    bf16x8 b = *(const bf16x8*)&Bs[f * 512 + lane * 8];
                    aW[f >> 2] = MFMA(ax[f & 3], b, aW[f >> 2]);
                }
#pragma unroll
                for (int f = 16; f < 32; ++f) {
                    bf16x8 b = *(const bf16x8*)&Bs[f * 512 + lane * 8];
                    aU[(f - 16) >> 2] = MFMA(ah[(f - 16) & 3], b, aU[(f - 16) >> 2]);
                }
            }
        }

        // ---- epilogue (type uniform per wave subtile) ----
        if (alive) {
#pragma unroll
            for (int r = 0; r < 4; ++r) {
                int rowe = wv * 16 + quad * 4 + r;
                int node = nid[rowe];
                int bl = node >> lvl;
                float pi, pf, po, pu, frv = 0.f, cr = 0.f;
                if (stBin) {
                    pi = aW[0][r] + aB[0][r];
                    pf = aW[1][r] + aB[1][r];
                    po = aW[2][r] + aB[3][r];
                    pu = aW[3][r] + aB[4][r];
                    frv = sigm(aW[1][r] + aB[2][r]);
                    cr = crv[r];
                } else {
                    pi = aW[0][r] + aU[0][r];
                    pf = aW[1][r] + aU[1][r];
                    po = aW[2][r] + aU[2][r];
                    pu = aW[3][r] + aU[3][r];
                }
                float ig = sigm(pi), fg = sigm(pf), og = sigm(po), ug = tanh_(pu);
                float c = ig * ug + fg * clv[r] + frv * cr;
                float h = og * tanh_(c);
                if (isRoot) {
                    rootH[(long)(treeOff + bl) * 128 + j] = h;
                    rootC[(long)(treeOff + bl) * 128 + j] = c;
                } else {
                    cOut[((long)jc * Mtot + node) * 16 + l16] = c;
                    hst[wv][quad * 4 + r][l16] = f2s(h);
                }
            }
        }
        if (!isRoot && alive) {
            int nloc = lane >> 2, c0 = (lane & 3) * 4;
            int roww = wv * 16 + nloc;
            int node = nid[roww];
            uint2 v = *(const uint2*)&hst[wv][nloc][c0];
            *(uint2*)&hOut[((long)jc * Mtot + node) * 16 + c0] = v;
        }
        __syncthreads();   // Bs reuse guard for next jc
    }
}

// ---- output: rootH/rootC fp32 -> d_out ----
__global__ __launch_bounds__(256) void out_kernel(const float* ws, void* out)
{
    const int isbf = ((const int*)ws)[0];
    const float* rootH = ws + OFF_ROOT;
    const float* rootC = rootH + 32768;
    int t = blockIdx.x * 256 + threadIdx.x;
    float h = rootH[t], c = rootC[t];
    if (isbf) {
        ((__hip_bfloat16*)out)[t]         = __float2bfloat16(h);
        ((__hip_bfloat16*)out)[32768 + t] = __float2bfloat16(c);
    } else {
        ((float*)out)[t]         = h;
        ((float*)out)[32768 + t] = c;
    }
}

extern "C" void kernel_launch(void* const* d_in, const int* in_sizes, int n_in,
                              void* d_out, int out_size, void* d_ws, size_t ws_size,
                              hipStream_t stream)
{
    const int* tokens = (const int*)d_in[0];
    const int* arity  = (const int*)d_in[1];
    const void* emb   = d_in[2];
    const void* W     = d_in[3];
    const void* bW    = d_in[4];
    const void* Ubin  = d_in[5];
    const void* bUbin = d_in[6];
    const void* Uun   = d_in[7];
    const void* bUun  = d_in[8];

    float* ws = (float*)d_ws;
    int* ws_i = (int*)d_ws;

    int Bc = 256;
    while (Bc > 1 && (size_t)(OFF_CHUNK + Bc * PER_TREE) * 4 > ws_size) Bc >>= 1;
    const int nCh = 256 / Bc;
    int bcsh = 0; while ((1 << bcsh) < Bc) ++bcsh;
    const int lstride = 255 * Bc + 512;
    const int nPairs = nCh * 8;

    hipMemsetAsync(ws_i + OFF_CNT, 0, 8192 * sizeof(int), stream);  // cnt + pos
    detect_kernel<<<1, 64, 0, stream>>>(W, ws);
    repack_mfma<<<128, 256, 0, stream>>>(W, bW, Ubin, bUbin, Uun, bUun, ws);
    count_kernel<<<256, 256, 0, stream>>>(arity, ws_i, bcsh);
    hdr_kernel<<<1, 256, 0, stream>>>(ws_i, nPairs);
    scatter_kernel<<<256, 256, 0, stream>>>(arity, ws_i, bcsh, Bc, lstride);
    pad_kernel<<<1, 256, 0, stream>>>(ws_i, nPairs, Bc, lstride);

    short* Ha = (short*)(ws + OFF_CHUNK);
    short* Hb = Ha + (long)Bc * 32768;
    float* Ca = (float*)(Hb + (long)Bc * 16384);
    float* Cb = Ca + (long)Bc * 8192;
    float* rootH = ws + OFF_ROOT;
    float* rootC = rootH + 32768;

    for (int cidx = 0; cidx < nCh; ++cidx) {
        int toff = cidx * Bc;
        {
            int Mleaf = Bc * 256;
            int NBL = (Mleaf + 63) / 64; if (NBL > 512) NBL = 512;
            int itersL = (Mleaf + NBL * 64 - 1) / (NBL * 64);
            leaf_mfma<<<NBL, 256, 0, stream>>>(tokens, emb, ws, Ha, toff, Mleaf, itersL);
        }
        for (int l = 7; l >= 0; --l) {
            int M = Bc << l;
            int Mchild = Bc << (l + 1);
            int nb = (M + 32 + 63) / 64;
            int js = 1;
            while (js < 8 && nb * js < 1024) js <<= 1;
            int jcc = 8 / js;
            const short* hC = (l & 1) ? Ha : Hb;
            const float* cC = (l & 1) ? Ca : Cb;
            short* hO = (l & 1) ? Hb : Ha;
            float* cO = (l & 1) ? Cb : Ca;
            int lc = (l == 7) ? 1 : 0;
            int isRoot = (l == 0) ? 1 : 0;
            int hdrIdx = cidx * 8 + l;
            int lbase = cidx * lstride + Bc * ((1 << l) - 1) + 64 * l;
            dim3 grid(nb * js);
            if (jcc == 8)
                level_mfma<8><<<grid, 256, 0, stream>>>(tokens, emb, ws, hC, cC, hO, cO,
                    rootH, rootC, l, toff, lc, isRoot, M, Mchild, nb, hdrIdx, lbase);
            else if (jcc == 4)
                level_mfma<4><<<grid, 256, 0, stream>>>(tokens, emb, ws, hC, cC, hO, cO,
                    rootH, rootC, l, toff, lc, isRoot, M, Mchild, nb, hdrIdx, lbase);
            else if (jcc == 2)
                level_mfma<2><<<grid, 256, 0, stream>>>(tokens, emb, ws, hC, cC, hO, cO,
                    rootH, rootC, l, toff, lc, isRoot, M, Mchild, nb, hdrIdx, lbase);
            else
                level_mfma<1><<<grid, 256, 0, stream>>>(tokens, emb, ws, hC, cC, hO, cO,
                    rootH, rootC, l, toff, lc, isRoot, M, Mchild, nb, hdrIdx, lbase);
        }
    }
    out_kernel<<<128, 256, 0, stream>>>(ws, d_out);
}

// Round 10
// 349.082 us; speedup vs baseline: 2.9694x; 2.9694x over previous
//
#include <hip/hip_runtime.h>
#include <hip/hip_bf16.h>

#define NTOK 511
#define NINT 255

typedef unsigned short u16;
typedef __attribute__((ext_vector_type(8))) short bf16x8;
typedef __attribute__((ext_vector_type(4))) float f32x4;

// ---- workspace layout (4-byte offsets) ----
constexpr int OFF_FLAG = 0;                 // [0] dtype flag
constexpr int OFF_WB   = 4;                 // bf16 weight region
// binW: [jc][56 frags]: f0-15 Wx(g=f>>2,ks=f&3); f16-55 Ub(g=(f-16)>>3,ks=(f-16)&7)
// unW:  [jc][16 frags]: Uu(g=f>>2,ks=f&3)
constexpr int BINW = 0;                     // 8*56*512 = 229376 bf16
constexpr int UNW  = 229376;                // 8*16*512 = 65536
constexpr int W3B  = 294912;                // 8*4*512  = 16384
constexpr int WB_ELEMS = 311296;
constexpr int OFF_BIAS = OFF_WB + WB_ELEMS / 2;      // 155652
constexpr int BW4 = 0, BUB4 = 512, BUB1 = 1024, BUU4 = 1152, B3 = 1664;
constexpr int BIAS_FLOATS = 1792;
constexpr int OFF_ROOT = OFF_BIAS + BIAS_FLOATS;     // 157444: rootH 32768 + rootC 32768
constexpr int OFF_HDR  = OFF_ROOT + 65536;           // hdr[cidx][l][4]           (8192)
constexpr int OFF_LIST = OFF_HDR + 8192;             // node lists                (196608)
constexpr int OFF_CHUNK = OFF_LIST + 196608 + 28;    // 16B-aligned
constexpr long PER_TREE = 49152;            // floats: Ha bf16 + Hb bf16 + Ca f32 + Cb f32

__device__ __forceinline__ float bf2f(__hip_bfloat16 v) { return __bfloat162float(v); }
__device__ __forceinline__ short f2s(float f) {
    __hip_bfloat16 b = __float2bfloat16(f);
    return *reinterpret_cast<short*>(&b);
}
__device__ __forceinline__ float sigm(float x) { return 1.0f / (1.0f + __expf(-x)); }
__device__ __forceinline__ float tanh_(float x) { return 1.0f - 2.0f / (__expf(2.0f * x) + 1.0f); }

__device__ __forceinline__ float ldf(const void* p, long idx, int isbf) {
    return isbf ? bf2f(((const __hip_bfloat16*)p)[idx]) : ((const float*)p)[idx];
}

__device__ __forceinline__ bf16x8 ldA(const void* p, long idx, int isbf) {
    if (isbf) return *(const bf16x8*)((const short*)p + idx);
    const float* f = (const float*)p + idx;
    float4 a = *(const float4*)f, b = *(const float4*)(f + 4);
    bf16x8 r;
    r[0] = f2s(a.x); r[1] = f2s(a.y); r[2] = f2s(a.z); r[3] = f2s(a.w);
    r[4] = f2s(b.x); r[5] = f2s(b.y); r[6] = f2s(b.z); r[7] = f2s(b.w);
    return r;
}

// async global->LDS 16B
typedef const __attribute__((address_space(1))) unsigned int* gp1_t;
typedef __attribute__((address_space(3))) unsigned int* lp3_t;
__device__ __forceinline__ void stage16(const void* g, void* l) {
    __builtin_amdgcn_global_load_lds((gp1_t)g, (lp3_t)l, 16, 0, 0);
}
__device__ __forceinline__ void stageF(const short* g, short* l, int t, int frags) {
    int iters = frags >> 2;
    for (int s = 0; s < iters; ++s) {
        int off = (s * 256 + t) * 8;
        stage16(g + off, l + off);
    }
}

// ---- dtype detection ----
__global__ void detect_kernel(const void* W, float* ws) {
    if (threadIdx.x == 0 && blockIdx.x == 0) {
        const u16* u = (const u16*)W;
        int cnt = 0;
        for (int i = 0; i < 128; i += 2) {
            u16 x = u[i];
            int ex = (x >> 7) & 0xff;
            if (x == 0 || (ex >= 96 && ex <= 127)) cnt++;
        }
        ((int*)ws)[0] = (cnt >= 48) ? 1 : 0;
    }
}

// ---- repack: raw weights -> type-split bf16 frag-linear + fp32 biases ----
__global__ __launch_bounds__(256) void repack_mfma(
    const void* W, const void* bW, const void* Ubin, const void* bUbin,
    const void* Uun, const void* bUun, float* ws)
{
    const int isbf = ((const int*)ws)[0];
    short* wb = (short*)(ws + OFF_WB);
    float* bias = ws + OFF_BIAS;
    int tid = blockIdx.x * blockDim.x + threadIdx.x;
    int nth = gridDim.x * blockDim.x;

    for (int idx = tid; idx < 229376; idx += nth) {
        int e = idx & 511, fjc = idx >> 9;
        int jc = fjc / 56, f = fjc - jc * 56;
        int lane = e >> 3, id8 = e & 7;
        int j = jc * 16 + (lane & 15);
        float v;
        if (f < 16) {
            int g = f >> 2, ks = f & 3;
            int k = ks * 32 + (lane >> 4) * 8 + id8;
            v = ldf(W, (long)g * 16384 + k * 128 + j, isbf);
        } else {
            int fb = f - 16; int g = fb >> 3, ks = fb & 7;
            int k = ks * 32 + (lane >> 4) * 8 + id8;
            v = ldf(Ubin, (long)g * 32768 + k * 128 + j, isbf);
        }
        wb[BINW + idx] = f2s(v);
    }
    for (int idx = tid; idx < 65536; idx += nth) {
        int e = idx & 511, fjc = idx >> 9;
        int jc = fjc >> 4, f = fjc & 15;
        int lane = e >> 3, id8 = e & 7;
        int g = f >> 2, ks = f & 3;
        int k = ks * 32 + (lane >> 4) * 8 + id8;
        int j = jc * 16 + (lane & 15);
        wb[UNW + idx] = f2s(ldf(Uun, (long)g * 16384 + k * 128 + j, isbf));
    }
    for (int idx = tid; idx < 16384; idx += nth) {
        int e = idx & 511, frag = idx >> 9;
        int jc = frag >> 2, ks = frag & 3;
        int lane = e >> 3, id8 = e & 7;
        int k = ks * 32 + (lane >> 4) * 8 + id8;
        int j = jc * 16 + (lane & 15);
        wb[W3B + idx] = f2s(ldf(W, (long)3 * 16384 + k * 128 + j, isbf));
    }
    for (int j = tid; j < 128; j += nth) {
        float4 b;
        b.x = ldf(bW, 0 * 128 + j, isbf); b.y = ldf(bW, 1 * 128 + j, isbf);
        b.z = ldf(bW, 2 * 128 + j, isbf); b.w = ldf(bW, 3 * 128 + j, isbf);
        ((float4*)(bias + BW4))[j] = b;
        float4 bb;
        bb.x = ldf(bUbin, 0 * 128 + j, isbf); bb.y = ldf(bUbin, 1 * 128 + j, isbf);
        bb.z = ldf(bUbin, 2 * 128 + j, isbf); bb.w = ldf(bUbin, 3 * 128 + j, isbf);
        ((float4*)(bias + BUB4))[j] = bb;
        (bias + BUB1)[j] = ldf(bUbin, 4 * 128 + j, isbf);
        float4 bu;
        bu.x = ldf(bUun, 0 * 128 + j, isbf); bu.y = ldf(bUun, 1 * 128 + j, isbf);
        bu.z = ldf(bUun, 2 * 128 + j, isbf); bu.w = ldf(bUun, 3 * 128 + j, isbf);
        ((float4*)(bias + BUU4))[j] = bu;
        (bias + B3)[j] = ldf(bW, 3 * 128 + j, isbf);
    }
}

// ---- prepass: arity-partitioned node lists; ONE block per (chunk, level).
//      Ballot-aggregated LDS atomics (2 per wave-iter) — no global atomics. ----
__global__ __launch_bounds__(256) void build_lists(
    const int* __restrict__ arity, int* __restrict__ ws_i,
    int bcsh, int Bc, int lstride)
{
    const int pairIdx = blockIdx.x;          // cidx*8 + l
    const int cidx = pairIdx >> 3, l = pairIdx & 7;
    const int nNodes = Bc << l;
    const int o2 = (1 << l) - 1;
    const int t = threadIdx.x, lane = t & 63;
    __shared__ int cntB, cntU, posB, posU;
    if (t == 0) { cntB = 0; cntU = 0; posB = 0; posU = 0; }
    __syncthreads();

    // pass 1: count (uniform loop bound -> lane 0 always active)
    for (int p0 = 0; p0 < nNodes; p0 += 256) {
        int p = p0 + t;
        bool valid = (p < nNodes);
        bool bin = false;
        if (valid) {
            int bl = p >> l, i = p - (bl << l);
            int b = (cidx << bcsh) + bl;
            bin = (arity[(long)b * NINT + o2 + i] == 1);
        }
        unsigned long long mB = __ballot(valid && bin);
        unsigned long long mU = __ballot(valid && !bin);
        if (lane == 0) {
            atomicAdd(&cntB, __popcll(mB));
            atomicAdd(&cntU, __popcll(mU));
        }
    }
    __syncthreads();
    const int nbin = cntB, nun = cntU;
    const int B16 = (nbin + 15) & ~15;
    const int T = B16 + ((nun + 15) & ~15);
    if (t == 0) {
        int* h = ws_i + OFF_HDR + pairIdx * 4;
        h[0] = nbin; h[1] = B16; h[2] = T; h[3] = nun;
    }
    int* lst = ws_i + OFF_LIST + cidx * lstride + Bc * o2 + 64 * l;

    // pass 2: scatter (ballot-aggregated positions)
    for (int p0 = 0; p0 < nNodes; p0 += 256) {
        int p = p0 + t;
        bool valid = (p < nNodes);
        bool bin = false;
        if (valid) {
            int bl = p >> l, i = p - (bl << l);
            int b = (cidx << bcsh) + bl;
            bin = (arity[(long)b * NINT + o2 + i] == 1);
        }
        unsigned long long mB = __ballot(valid && bin);
        unsigned long long mU = __ballot(valid && !bin);
        int baseB = 0, baseU = 0;
        if (lane == 0) {
            baseB = atomicAdd(&posB, __popcll(mB));
            baseU = atomicAdd(&posU, __popcll(mU));
        }
        baseB = __shfl(baseB, 0);
        baseU = __shfl(baseU, 0);
        unsigned long long lt = ((unsigned long long)1 << lane) - 1;
        if (valid) {
            if (bin) lst[baseB + __popcll(mB & lt)] = p;
            else     lst[B16 + baseU + __popcll(mU & lt)] = p;
        }
    }
    __syncthreads();
    // pad partitions to 16-multiples with duplicates (benign redundant writes)
    for (int s = nbin + t; s < B16; s += 256) lst[s] = lst[0];
    for (int s = B16 + nun + t; s < T; s += 256) lst[s] = lst[B16];
}

#define MFMA(A, B, C) __builtin_amdgcn_mfma_f32_16x16x32_bf16(A, B, C, 0, 0, 0)

// ---- leaf: h = tanh(x @ W3 + b3); W3 in registers, no barriers ----
__global__ __launch_bounds__(256, 2) void leaf_mfma(
    const int* __restrict__ tokens, const void* emb, const float* __restrict__ ws,
    short* __restrict__ hOut, int treeOff, int Mtot, int iters)
{
    __shared__ short hst[4][16][132];
    const int t = threadIdx.x;
    const int isbf = ((const int*)ws)[0];
    const int wv = t >> 6, lane = t & 63, quad = lane >> 4, l16 = lane & 15;
    const short* wb = (const short*)(ws + OFF_WB);
    const float* bias = ws + OFF_BIAS;

    bf16x8 bf[32];
#pragma unroll
    for (int f = 0; f < 32; ++f)
        bf[f] = *(const bf16x8*)(wb + W3B + f * 512 + lane * 8);
    float b3v[8];
#pragma unroll
    for (int jc = 0; jc < 8; ++jc) b3v[jc] = (bias + B3)[jc * 16 + l16];

    for (int it = 0; it < iters; ++it) {
        int rb = (blockIdx.x * iters + it) * 64 + wv * 16;
        if (rb >= Mtot) break;
        int p = rb + l16; if (p >= Mtot) p = Mtot - 1;
        int bl = p >> 8, i = p & 255;
        int tk = tokens[(long)(treeOff + bl) * NTOK + 255 + i];
        bf16x8 ax[4];
#pragma unroll
        for (int ks = 0; ks < 4; ++ks)
            ax[ks] = ldA(emb, (long)tk * 128 + ks * 32 + quad * 8, isbf);
        f32x4 acc[8];
#pragma unroll
        for (int jc = 0; jc < 8; ++jc) acc[jc] = {0.f, 0.f, 0.f, 0.f};
#pragma unroll
        for (int jc = 0; jc < 8; ++jc)
#pragma unroll
            for (int ks = 0; ks < 4; ++ks)
                acc[jc] = MFMA(ax[ks], bf[jc * 4 + ks], acc[jc]);
#pragma unroll
        for (int jc = 0; jc < 8; ++jc)
#pragma unroll
            for (int r = 0; r < 4; ++r)
                hst[wv][quad * 4 + r][jc * 16 + l16] = f2s(tanh_(acc[jc][r] + b3v[jc]));
        int nloc = lane >> 2, c0 = (lane & 3) * 4;
        int prow = rb + nloc;
        if (prow < Mtot) {
#pragma unroll
            for (int jcb = 0; jcb < 8; ++jcb) {
                uint2 v = *(const uint2*)&hst[wv][nloc][jcb * 16 + c0];
                *(uint2*)&hOut[((long)jcb * Mtot + prow) * 16 + c0] = v;
            }
        }
    }
}

// ---- internal level: arity-sorted 64-node blocks, type-pure 16-node subtiles ----
template <int JCC>
__global__ __launch_bounds__(256, 3) void level_mfma(
    const int* __restrict__ tokens, const void* emb,
    const float* __restrict__ ws, const short* __restrict__ hChild,
    const float* __restrict__ cChild, short* __restrict__ hOut, float* __restrict__ cOut,
    float* __restrict__ rootH, float* __restrict__ rootC,
    int lvl, int treeOff, int leafchild, int isRoot, int Mtot, int Mchild,
    int NBM, int hdrIdx, int lbase)
{
    __shared__ short Bs[32 * 512];        // 32 KB stage buffer
    __shared__ short hst[4][16][20];      // wave-private h transpose
    __shared__ int nid[64];
    __shared__ int tokL[64];

    const int t = threadIdx.x;
    const int isbf = ((const int*)ws)[0];
    const int jsx = blockIdx.x / NBM, mb = blockIdx.x - jsx * NBM;
    const int jcLo = jsx * JCC;
    const int p0 = mb * 64;
    const int* hdr = (const int*)ws + OFF_HDR + hdrIdx * 4;
    const int B16 = hdr[1], T = hdr[2];
    if (p0 >= T) return;
    const int* list = (const int*)ws + OFF_LIST + lbase;
    const int wv = t >> 6, lane = t & 63, quad = lane >> 4, l16 = lane & 15;
    const int cnt = 1 << lvl, o2 = cnt - 1;
    const short* wb = (const short*)(ws + OFF_WB);
    const float* bias = ws + OFF_BIAS;

    if (t < 64) {
        int pos = p0 + t; if (pos >= T) pos = T - 1;
        int node = list[pos];
        nid[t] = node;
        int bl = node >> lvl, i = node - (bl << lvl);
        tokL[t] = tokens[(long)(treeOff + bl) * NTOK + o2 + i];
    }
    __syncthreads();

    const int sPos = p0 + wv * 16;
    const bool stBin = (sPos < B16);
    const bool alive = (sPos < T);
    const bool hasBin = (p0 < B16);
    const int hiPos = (p0 + 64 < T) ? (p0 + 64) : T;
    const bool hasUn = (hiPos > B16);

    // A-fragments
    bf16x8 ax[4], ah[8];
    {
        int row = wv * 16 + l16;
        int node = nid[row];
        int bl = node >> lvl, i = node - (bl << lvl);
        long crow = (long)bl * (cnt << 1) + 2 * i;
        int tk = tokL[row];
#pragma unroll
        for (int ks = 0; ks < 4; ++ks)
            ax[ks] = ldA(emb, (long)tk * 128 + ks * 32 + quad * 8, isbf);
#pragma unroll
        for (int ks = 0; ks < 8; ++ks) {
            int k0 = ks * 32 + quad * 8;
            int side = k0 >> 7, kl = k0 & 127;
            ah[ks] = *(const bf16x8*)(hChild +
                ((long)(kl >> 4) * Mchild + crow + side) * 16 + (kl & 15));
        }
    }

    for (int jx = 0; jx < JCC; ++jx) {
        const int jc = jcLo + jx;
        const short* wbin = wb + BINW + (long)jc * (56 * 512);
        const short* wun  = wb + UNW  + (long)jc * (16 * 512);
        const int j = jc * 16 + l16;
        const float4 bw = ((const float4*)(bias + BW4))[j];
        const float4 bb = ((const float4*)(bias + BUB4))[j];
        const float  b1 = (bias + BUB1)[j];
        const float4 bu = ((const float4*)(bias + BUU4))[j];

        // c prefetch for this jc
        float clv[4], crv[4];
#pragma unroll
        for (int r = 0; r < 4; ++r) {
            clv[r] = 0.f; crv[r] = 0.f;
            if (!leafchild) {
                int rowe = wv * 16 + quad * 4 + r;
                int node = nid[rowe];
                int bl = node >> lvl, i = node - (bl << lvl);
                long crowe = (long)bl * (cnt << 1) + 2 * i;
                clv[r] = cChild[((long)jc * Mchild + crowe) * 16 + l16];
                if (stBin) crv[r] = cChild[((long)jc * Mchild + crowe + 1) * 16 + l16];
            }
        }

        // bias-folded accumulator init
        f32x4 aW[4], aB[5], aU[4];
        aW[0] = (f32x4){bw.x, bw.x, bw.x, bw.x};
        aW[1] = (f32x4){bw.y, bw.y, bw.y, bw.y};
        aW[2] = (f32x4){bw.z, bw.z, bw.z, bw.z};
        aW[3] = (f32x4){bw.w, bw.w, bw.w, bw.w};
        aB[0] = (f32x4){bb.x, bb.x, bb.x, bb.x};
        aB[1] = (f32x4){bb.y, bb.y, bb.y, bb.y};
        aB[2] = (f32x4){bb.z, bb.z, bb.z, bb.z};
        aB[3] = (f32x4){bb.w, bb.w, bb.w, bb.w};
        aB[4] = (f32x4){b1, b1, b1, b1};
        aU[0] = (f32x4){bu.x, bu.x, bu.x, bu.x};
        aU[1] = (f32x4){bu.y, bu.y, bu.y, bu.y};
        aU[2] = (f32x4){bu.z, bu.z, bu.z, bu.z};
        aU[3] = (f32x4){bu.w, bu.w, bu.w, bu.w};

        if (hasBin) {
            stageF(wbin, Bs, t, 32);
            __syncthreads();
            if (alive) {
#pragma unroll
                for (int f = 0; f < 16; ++f) {
                    bf16x8 b = *(const bf16x8*)&Bs[f * 512 + lane * 8];
                    aW[f >> 2] = MFMA(ax[f & 3], b, aW[f >> 2]);
                }
            }
            if (stBin) {
#pragma unroll
                for (int f = 16; f < 32; ++f) {
                    bf16x8 b = *(const bf16x8*)&Bs[f * 512 + lane * 8];
                    int fb = f - 16;
                    aB[fb >> 3] = MFMA(ah[fb & 7], b, aB[fb >> 3]);
                }
            }
            __syncthreads();
            stageF(wbin + 32 * 512, Bs, t, 24);
            __syncthreads();
            if (stBin) {
#pragma unroll
                for (int f = 0; f < 24; ++f) {
                    bf16x8 b = *(const bf16x8*)&Bs[f * 512 + lane * 8];
                    int fb = f + 16;
                    aB[fb >> 3] = MFMA(ah[fb & 7], b, aB[fb >> 3]);
                }
            }
            if (hasUn) {
                __syncthreads();
                stageF(wun, Bs, t, 16);
                __syncthreads();
                if (alive && !stBin) {
#pragma unroll
                    for (int f = 0; f < 16; ++f) {
                        bf16x8 b = *(const bf16x8*)&Bs[f * 512 + lane * 8];
                        aU[f >> 2] = MFMA(ah[f & 3], b, aU[f >> 2]);
                    }
                }
            }
        } else {
            stageF(wbin, Bs, t, 16);
            stageF(wun, Bs + 16 * 512, t, 16);
            __syncthreads();
            if (alive) {
#pragma unroll
                for (int f = 0; f < 16; ++f) {
                    bf16x8 b = *(const bf16x8*)&Bs[f * 512 + lane * 8];
                    aW[f >> 2] = MFMA(ax[f & 3], b, aW[f >> 2]);
                }
#pragma unroll
                for (int f = 16; f < 32; ++f) {
                    bf16x8 b = *(const bf16x8*)&Bs[f * 512 + lane * 8];
                    aU[(f - 16) >> 2] = MFMA(ah[(f - 16) & 3], b, aU[(f - 16) >> 2]);
                }
            }
        }

        // ---- epilogue (type uniform per wave subtile) ----
        if (alive) {
#pragma unroll
            for (int r = 0; r < 4; ++r) {
                int rowe = wv * 16 + quad * 4 + r;
                int node = nid[rowe];
                int bl = node >> lvl;
                float pi, pf, po, pu, frv = 0.f, cr = 0.f;
                if (stBin) {
                    pi = aW[0][r] + aB[0][r];
                    pf = aW[1][r] + aB[1][r];
                    po = aW[2][r] + aB[3][r];
                    pu = aW[3][r] + aB[4][r];
                    frv = sigm(aW[1][r] + aB[2][r]);
                    cr = crv[r];
                } else {
                    pi = aW[0][r] + aU[0][r];
                    pf = aW[1][r] + aU[1][r];
                    po = aW[2][r] + aU[2][r];
                    pu = aW[3][r] + aU[3][r];
                }
                float ig = sigm(pi), fg = sigm(pf), og = sigm(po), ug = tanh_(pu);
                float c = ig * ug + fg * clv[r] + frv * cr;
                float h = og * tanh_(c);
                if (isRoot) {
                    rootH[(long)(treeOff + bl) * 128 + j] = h;
                    rootC[(long)(treeOff + bl) * 128 + j] = c;
                } else {
                    cOut[((long)jc * Mtot + node) * 16 + l16] = c;
                    hst[wv][quad * 4 + r][l16] = f2s(h);
                }
            }
        }
        if (!isRoot && alive) {
            int nloc = lane >> 2, c0 = (lane & 3) * 4;
            int roww = wv * 16 + nloc;
            int node = nid[roww];
            uint2 v = *(const uint2*)&hst[wv][nloc][c0];
            *(uint2*)&hOut[((long)jc * Mtot + node) * 16 + c0] = v;
        }
        __syncthreads();   // Bs reuse guard for next jc
    }
}

// ---- output: rootH/rootC fp32 -> d_out ----
__global__ __launch_bounds__(256) void out_kernel(const float* ws, void* out)
{
    const int isbf = ((const int*)ws)[0];
    const float* rootH = ws + OFF_ROOT;
    const float* rootC = rootH + 32768;
    int t = blockIdx.x * 256 + threadIdx.x;
    float h = rootH[t], c = rootC[t];
    if (isbf) {
        ((__hip_bfloat16*)out)[t]         = __float2bfloat16(h);
        ((__hip_bfloat16*)out)[32768 + t] = __float2bfloat16(c);
    } else {
        ((float*)out)[t]         = h;
        ((float*)out)[32768 + t] = c;
    }
}

extern "C" void kernel_launch(void* const* d_in, const int* in_sizes, int n_in,
                              void* d_out, int out_size, void* d_ws, size_t ws_size,
                              hipStream_t stream)
{
    const int* tokens = (const int*)d_in[0];
    const int* arity  = (const int*)d_in[1];
    const void* emb   = d_in[2];
    const void* W     = d_in[3];
    const void* bW    = d_in[4];
    const void* Ubin  = d_in[5];
    const void* bUbin = d_in[6];
    const void* Uun   = d_in[7];
    const void* bUun  = d_in[8];

    float* ws = (float*)d_ws;
    int* ws_i = (int*)d_ws;

    int Bc = 256;
    while (Bc > 1 && (size_t)(OFF_CHUNK + Bc * PER_TREE) * 4 > ws_size) Bc >>= 1;
    const int nCh = 256 / Bc;
    int bcsh = 0; while ((1 << bcsh) < Bc) ++bcsh;
    const int lstride = 255 * Bc + 512;
    const int nPairs = nCh * 8;

    detect_kernel<<<1, 64, 0, stream>>>(W, ws);
    repack_mfma<<<128, 256, 0, stream>>>(W, bW, Ubin, bUbin, Uun, bUun, ws);
    build_lists<<<nPairs, 256, 0, stream>>>(arity, ws_i, bcsh, Bc, lstride);

    short* Ha = (short*)(ws + OFF_CHUNK);
    short* Hb = Ha + (long)Bc * 32768;
    float* Ca = (float*)(Hb + (long)Bc * 16384);
    float* Cb = Ca + (long)Bc * 8192;
    float* rootH = ws + OFF_ROOT;
    float* rootC = rootH + 32768;

    for (int cidx = 0; cidx < nCh; ++cidx) {
        int toff = cidx * Bc;
        {
            int Mleaf = Bc * 256;
            int NBL = (Mleaf + 63) / 64; if (NBL > 512) NBL = 512;
            int itersL = (Mleaf + NBL * 64 - 1) / (NBL * 64);
            leaf_mfma<<<NBL, 256, 0, stream>>>(tokens, emb, ws, Ha, toff, Mleaf, itersL);
        }
        for (int l = 7; l >= 0; --l) {
            int M = Bc << l;
            int Mchild = Bc << (l + 1);
            int nb = (M + 32 + 63) / 64;
            int js = 1;
            while (js < 8 && nb * js < 1024) js <<= 1;
            int jcc = 8 / js;
            const short* hC = (l & 1) ? Ha : Hb;
            const float* cC = (l & 1) ? Ca : Cb;
            short* hO = (l & 1) ? Hb : Ha;
            float* cO = (l & 1) ? Cb : Ca;
            int lc = (l == 7) ? 1 : 0;
            int isRoot = (l == 0) ? 1 : 0;
            int hdrIdx = cidx * 8 + l;
            int lbase = cidx * lstride + Bc * ((1 << l) - 1) + 64 * l;
            dim3 grid(nb * js);
            if (jcc == 8)
                level_mfma<8><<<grid, 256, 0, stream>>>(tokens, emb, ws, hC, cC, hO, cO,
                    rootH, rootC, l, toff, lc, isRoot, M, Mchild, nb, hdrIdx, lbase);
            else if (jcc == 4)
                level_mfma<4><<<grid, 256, 0, stream>>>(tokens, emb, ws, hC, cC, hO, cO,
                    rootH, rootC, l, toff, lc, isRoot, M, Mchild, nb, hdrIdx, lbase);
            else if (jcc == 2)
                level_mfma<2><<<grid, 256, 0, stream>>>(tokens, emb, ws, hC, cC, hO, cO,
                    rootH, rootC, l, toff, lc, isRoot, M, Mchild, nb, hdrIdx, lbase);
            else
                level_mfma<1><<<grid, 256, 0, stream>>>(tokens, emb, ws, hC, cC, hO, cO,
                    rootH, rootC, l, toff, lc, isRoot, M, Mchild, nb, hdrIdx, lbase);
        }
    }
    out_kernel<<<128, 256, 0, stream>>>(ws, d_out);
}

// Round 11
// 275.037 us; speedup vs baseline: 3.7689x; 1.2692x over previous
//
#include <hip/hip_runtime.h>
#include <hip/hip_bf16.h>

#define NTOK 511
#define NINT 255

typedef unsigned short u16;
typedef __attribute__((ext_vector_type(8))) short bf16x8;
typedef __attribute__((ext_vector_type(4))) float f32x4;

// ---- workspace layout (4-byte offsets) ----
constexpr int OFF_FLAG = 0;                 // [0] dtype flag
constexpr int OFF_WB   = 4;                 // bf16 weight region
// binW: [jc][56 frags]: f0-15 Wx(g=f>>2,ks=f&3); f16-55 Ub(g=(f-16)>>3,ks=(f-16)&7)
// unW:  [jc][16 frags]: Uu(g=f>>2,ks=f&3)
constexpr int BINW = 0;                     // 8*56*512 = 229376 bf16
constexpr int UNW  = 229376;                // 8*16*512 = 65536
constexpr int W3B  = 294912;                // 8*4*512  = 16384
constexpr int WB_ELEMS = 311296;
constexpr int OFF_BIAS = OFF_WB + WB_ELEMS / 2;      // 155652
constexpr int BW4 = 0, BUB4 = 512, BUB1 = 1024, BUU4 = 1152, B3 = 1664;
constexpr int BIAS_FLOATS = 1792;
constexpr int OFF_ROOT = OFF_BIAS + BIAS_FLOATS;     // 157444: rootH 32768 + rootC 32768
constexpr int OFF_HDR  = OFF_ROOT + 65536;           // hdr[pair][4]          (8192)
constexpr int OFF_SEGC = OFF_HDR + 8192;             // seg (cntB,cntU,baseB,baseU) (8192)
constexpr int OFF_LIST = OFF_SEGC + 8192;            // node lists            (196608)
constexpr int OFF_CHUNK = OFF_LIST + 196608 + 28;    // 16B-aligned
constexpr long PER_TREE = 49152;            // floats: Ha bf16 + Hb bf16 + Ca f32 + Cb f32

__device__ __forceinline__ float bf2f(__hip_bfloat16 v) { return __bfloat162float(v); }
__device__ __forceinline__ short f2s(float f) {
    __hip_bfloat16 b = __float2bfloat16(f);
    return *reinterpret_cast<short*>(&b);
}
__device__ __forceinline__ float sigm(float x) { return 1.0f / (1.0f + __expf(-x)); }
__device__ __forceinline__ float tanh_(float x) { return 1.0f - 2.0f / (__expf(2.0f * x) + 1.0f); }

__device__ __forceinline__ float ldf(const void* p, long idx, int isbf) {
    return isbf ? bf2f(((const __hip_bfloat16*)p)[idx]) : ((const float*)p)[idx];
}

__device__ __forceinline__ bf16x8 ldA(const void* p, long idx, int isbf) {
    if (isbf) return *(const bf16x8*)((const short*)p + idx);
    const float* f = (const float*)p + idx;
    float4 a = *(const float4*)f, b = *(const float4*)(f + 4);
    bf16x8 r;
    r[0] = f2s(a.x); r[1] = f2s(a.y); r[2] = f2s(a.z); r[3] = f2s(a.w);
    r[4] = f2s(b.x); r[5] = f2s(b.y); r[6] = f2s(b.z); r[7] = f2s(b.w);
    return r;
}

// async global->LDS 16B
typedef const __attribute__((address_space(1))) unsigned int* gp1_t;
typedef __attribute__((address_space(3))) unsigned int* lp3_t;
__device__ __forceinline__ void stage16(const void* g, void* l) {
    __builtin_amdgcn_global_load_lds((gp1_t)g, (lp3_t)l, 16, 0, 0);
}
__device__ __forceinline__ void stageF(const short* g, short* l, int t, int frags) {
    int iters = frags >> 2;
    for (int s = 0; s < iters; ++s) {
        int off = (s * 256 + t) * 8;
        stage16(g + off, l + off);
    }
}

// ---- dtype detection ----
__global__ void detect_kernel(const void* W, float* ws) {
    if (threadIdx.x == 0 && blockIdx.x == 0) {
        const u16* u = (const u16*)W;
        int cnt = 0;
        for (int i = 0; i < 128; i += 2) {
            u16 x = u[i];
            int ex = (x >> 7) & 0xff;
            if (x == 0 || (ex >= 96 && ex <= 127)) cnt++;
        }
        ((int*)ws)[0] = (cnt >= 48) ? 1 : 0;
    }
}

// ---- repack: raw weights -> type-split bf16 frag-linear + fp32 biases ----
__global__ __launch_bounds__(256) void repack_mfma(
    const void* W, const void* bW, const void* Ubin, const void* bUbin,
    const void* Uun, const void* bUun, float* ws)
{
    const int isbf = ((const int*)ws)[0];
    short* wb = (short*)(ws + OFF_WB);
    float* bias = ws + OFF_BIAS;
    int tid = blockIdx.x * blockDim.x + threadIdx.x;
    int nth = gridDim.x * blockDim.x;

    for (int idx = tid; idx < 229376; idx += nth) {
        int e = idx & 511, fjc = idx >> 9;
        int jc = fjc / 56, f = fjc - jc * 56;
        int lane = e >> 3, id8 = e & 7;
        int j = jc * 16 + (lane & 15);
        float v;
        if (f < 16) {
            int g = f >> 2, ks = f & 3;
            int k = ks * 32 + (lane >> 4) * 8 + id8;
            v = ldf(W, (long)g * 16384 + k * 128 + j, isbf);
        } else {
            int fb = f - 16; int g = fb >> 3, ks = fb & 7;
            int k = ks * 32 + (lane >> 4) * 8 + id8;
            v = ldf(Ubin, (long)g * 32768 + k * 128 + j, isbf);
        }
        wb[BINW + idx] = f2s(v);
    }
    for (int idx = tid; idx < 65536; idx += nth) {
        int e = idx & 511, fjc = idx >> 9;
        int jc = fjc >> 4, f = fjc & 15;
        int lane = e >> 3, id8 = e & 7;
        int g = f >> 2, ks = f & 3;
        int k = ks * 32 + (lane >> 4) * 8 + id8;
        int j = jc * 16 + (lane & 15);
        wb[UNW + idx] = f2s(ldf(Uun, (long)g * 16384 + k * 128 + j, isbf));
    }
    for (int idx = tid; idx < 16384; idx += nth) {
        int e = idx & 511, frag = idx >> 9;
        int jc = frag >> 2, ks = frag & 3;
        int lane = e >> 3, id8 = e & 7;
        int k = ks * 32 + (lane >> 4) * 8 + id8;
        int j = jc * 16 + (lane & 15);
        wb[W3B + idx] = f2s(ldf(W, (long)3 * 16384 + k * 128 + j, isbf));
    }
    for (int j = tid; j < 128; j += nth) {
        float4 b;
        b.x = ldf(bW, 0 * 128 + j, isbf); b.y = ldf(bW, 1 * 128 + j, isbf);
        b.z = ldf(bW, 2 * 128 + j, isbf); b.w = ldf(bW, 3 * 128 + j, isbf);
        ((float4*)(bias + BW4))[j] = b;
        float4 bb;
        bb.x = ldf(bUbin, 0 * 128 + j, isbf); bb.y = ldf(bUbin, 1 * 128 + j, isbf);
        bb.z = ldf(bUbin, 2 * 128 + j, isbf); bb.w = ldf(bUbin, 3 * 128 + j, isbf);
        ((float4*)(bias + BUB4))[j] = bb;
        (bias + BUB1)[j] = ldf(bUbin, 4 * 128 + j, isbf);
        float4 bu;
        bu.x = ldf(bUun, 0 * 128 + j, isbf); bu.y = ldf(bUun, 1 * 128 + j, isbf);
        bu.z = ldf(bUun, 2 * 128 + j, isbf); bu.w = ldf(bUun, 3 * 128 + j, isbf);
        ((float4*)(bias + BUU4))[j] = bu;
        (bias + B3)[j] = ldf(bW, 3 * 128 + j, isbf);
    }
}

// ---- prepass (parallel, deterministic, no global atomics) ----
// grid: (nSegMax, nPairs). One block per 256-node segment.
__global__ __launch_bounds__(256) void count_seg(
    const int* __restrict__ arity, int* __restrict__ ws_i,
    int bcsh, int Bc, int nSegMax)
{
    const int pair = blockIdx.y, seg = blockIdx.x;
    const int cidx = pair >> 3, l = pair & 7;
    const int nNodes = Bc << l;
    if (seg * 256 >= nNodes) return;
    const int o2 = (1 << l) - 1;
    const int t = threadIdx.x, lane = t & 63, wv = t >> 6;
    __shared__ int wc[4][2];
    int p = seg * 256 + t;
    bool valid = (p < nNodes);
    bool bin = false;
    if (valid) {
        int bl = p >> l, i = p - (bl << l);
        int b = (cidx << bcsh) + bl;
        bin = (arity[(long)b * NINT + o2 + i] == 1);
    }
    unsigned long long mB = __ballot(valid && bin);
    unsigned long long mU = __ballot(valid && !bin);
    if (lane == 0) { wc[wv][0] = __popcll(mB); wc[wv][1] = __popcll(mU); }
    __syncthreads();
    if (t == 0) {
        int* sc = ws_i + OFF_SEGC + (pair * nSegMax + seg) * 4;
        sc[0] = wc[0][0] + wc[1][0] + wc[2][0] + wc[3][0];
        sc[1] = wc[0][1] + wc[1][1] + wc[2][1] + wc[3][1];
    }
}

__global__ void prefix_kernel(int* __restrict__ ws_i, int nPairs, int Bc, int nSegMax)
{
    for (int pair = threadIdx.x; pair < nPairs; pair += 256) {
        int l = pair & 7;
        int nNodes = Bc << l;
        int nSeg = (nNodes + 255) >> 8; if (nSeg < 1) nSeg = 1;
        int accB = 0, accU = 0;
        for (int s = 0; s < nSeg; ++s) {
            int* sc = ws_i + OFF_SEGC + (pair * nSegMax + s) * 4;
            int cb = sc[0], cu = sc[1];
            sc[2] = accB; sc[3] = accU;
            accB += cb; accU += cu;
        }
        int B16 = (accB + 15) & ~15;
        int T = B16 + ((accU + 15) & ~15);
        int* h = ws_i + OFF_HDR + pair * 4;
        h[0] = accB; h[1] = B16; h[2] = T; h[3] = accU;
    }
}

__global__ __launch_bounds__(256) void scatter_seg(
    const int* __restrict__ arity, int* __restrict__ ws_i,
    int bcsh, int Bc, int nSegMax, int lstride)
{
    const int pair = blockIdx.y, seg = blockIdx.x;
    const int cidx = pair >> 3, l = pair & 7;
    const int nNodes = Bc << l;
    if (seg * 256 >= nNodes) return;
    const int o2 = (1 << l) - 1;
    const int t = threadIdx.x, lane = t & 63, wv = t >> 6;
    __shared__ int wc[4][2];
    const int* sc = ws_i + OFF_SEGC + (pair * nSegMax + seg) * 4;
    const int segBaseB = sc[2], segBaseU = sc[3];
    const int B16 = ws_i[OFF_HDR + pair * 4 + 1];
    int* lst = ws_i + OFF_LIST + cidx * lstride + Bc * o2 + 64 * l;

    int p = seg * 256 + t;
    bool valid = (p < nNodes);
    bool bin = false;
    if (valid) {
        int bl = p >> l, i = p - (bl << l);
        int b = (cidx << bcsh) + bl;
        bin = (arity[(long)b * NINT + o2 + i] == 1);
    }
    unsigned long long mB = __ballot(valid && bin);
    unsigned long long mU = __ballot(valid && !bin);
    if (lane == 0) { wc[wv][0] = __popcll(mB); wc[wv][1] = __popcll(mU); }
    __syncthreads();
    int wBaseB = segBaseB, wBaseU = segBaseU;
    for (int w = 0; w < 4; ++w) {
        if (w < wv) { wBaseB += wc[w][0]; wBaseU += wc[w][1]; }
    }
    unsigned long long lt = ((unsigned long long)1 << lane) - 1;
    if (valid) {
        if (bin) lst[wBaseB + __popcll(mB & lt)] = p;
        else     lst[B16 + wBaseU + __popcll(mU & lt)] = p;
    }
}

__global__ void pad_kernel(int* __restrict__ ws_i, int nPairs, int Bc, int lstride)
{
    for (int pair = threadIdx.x; pair < nPairs; pair += 256) {
        int cidx = pair >> 3, l = pair & 7;
        int* h = ws_i + OFF_HDR + pair * 4;
        int nbin = h[0], B16 = h[1], T = h[2], nun = h[3];
        int* lst = ws_i + OFF_LIST + cidx * lstride + Bc * ((1 << l) - 1) + 64 * l;
        if (nbin > 0) for (int s = nbin; s < B16; ++s) lst[s] = lst[0];
        if (nun > 0)  for (int s = B16 + nun; s < T; ++s) lst[s] = lst[B16];
    }
}

#define MFMA(A, B, C) __builtin_amdgcn_mfma_f32_16x16x32_bf16(A, B, C, 0, 0, 0)

// ---- leaf: h = tanh(x @ W3 + b3); W3 in registers, no barriers ----
__global__ __launch_bounds__(256, 2) void leaf_mfma(
    const int* __restrict__ tokens, const void* emb, const float* __restrict__ ws,
    short* __restrict__ hOut, int treeOff, int Mtot, int iters)
{
    __shared__ short hst[4][16][132];
    const int t = threadIdx.x;
    const int isbf = ((const int*)ws)[0];
    const int wv = t >> 6, lane = t & 63, quad = lane >> 4, l16 = lane & 15;
    const short* wb = (const short*)(ws + OFF_WB);
    const float* bias = ws + OFF_BIAS;

    bf16x8 bf[32];
#pragma unroll
    for (int f = 0; f < 32; ++f)
        bf[f] = *(const bf16x8*)(wb + W3B + f * 512 + lane * 8);
    float b3v[8];
#pragma unroll
    for (int jc = 0; jc < 8; ++jc) b3v[jc] = (bias + B3)[jc * 16 + l16];

    for (int it = 0; it < iters; ++it) {
        int rb = (blockIdx.x * iters + it) * 64 + wv * 16;
        if (rb >= Mtot) break;
        int p = rb + l16; if (p >= Mtot) p = Mtot - 1;
        int bl = p >> 8, i = p & 255;
        int tk = tokens[(long)(treeOff + bl) * NTOK + 255 + i];
        bf16x8 ax[4];
#pragma unroll
        for (int ks = 0; ks < 4; ++ks)
            ax[ks] = ldA(emb, (long)tk * 128 + ks * 32 + quad * 8, isbf);
        f32x4 acc[8];
#pragma unroll
        for (int jc = 0; jc < 8; ++jc) acc[jc] = {0.f, 0.f, 0.f, 0.f};
#pragma unroll
        for (int jc = 0; jc < 8; ++jc)
#pragma unroll
            for (int ks = 0; ks < 4; ++ks)
                acc[jc] = MFMA(ax[ks], bf[jc * 4 + ks], acc[jc]);
#pragma unroll
        for (int jc = 0; jc < 8; ++jc)
#pragma unroll
            for (int r = 0; r < 4; ++r)
                hst[wv][quad * 4 + r][jc * 16 + l16] = f2s(tanh_(acc[jc][r] + b3v[jc]));
        int nloc = lane >> 2, c0 = (lane & 3) * 4;
        int prow = rb + nloc;
        if (prow < Mtot) {
#pragma unroll
            for (int jcb = 0; jcb < 8; ++jcb) {
                uint2 v = *(const uint2*)&hst[wv][nloc][jcb * 16 + c0];
                *(uint2*)&hOut[((long)jcb * Mtot + prow) * 16 + c0] = v;
            }
        }
    }
}

// ---- internal level: arity-sorted 64-node blocks, type-pure 16-node subtiles ----
template <int JCC>
__global__ __launch_bounds__(256, 3) void level_mfma(
    const int* __restrict__ tokens, const void* emb,
    const float* __restrict__ ws, const short* __restrict__ hChild,
    const float* __restrict__ cChild, short* __restrict__ hOut, float* __restrict__ cOut,
    float* __restrict__ rootH, float* __restrict__ rootC,
    int lvl, int treeOff, int leafchild, int isRoot, int Mtot, int Mchild,
    int NBM, int hdrIdx, int lbase)
{
    __shared__ short Bs[32 * 512];        // 32 KB stage buffer
    __shared__ short hst[4][16][20];      // wave-private h transpose
    __shared__ int nid[64];
    __shared__ int tokL[64];

    const int t = threadIdx.x;
    const int isbf = ((const int*)ws)[0];
    const int jsx = blockIdx.x / NBM, mb = blockIdx.x - jsx * NBM;
    const int jcLo = jsx * JCC;
    const int p0 = mb * 64;
    const int* hdr = (const int*)ws + OFF_HDR + hdrIdx * 4;
    const int B16 = hdr[1], T = hdr[2];
    if (p0 >= T) return;
    const int* list = (const int*)ws + OFF_LIST + lbase;
    const int wv = t >> 6, lane = t & 63, quad = lane >> 4, l16 = lane & 15;
    const int cnt = 1 << lvl, o2 = cnt - 1;
    const short* wb = (const short*)(ws + OFF_WB);
    const float* bias = ws + OFF_BIAS;

    if (t < 64) {
        int pos = p0 + t; if (pos >= T) pos = T - 1;
        int node = list[pos];
        nid[t] = node;
        int bl = node >> lvl, i = node - (bl << lvl);
        tokL[t] = tokens[(long)(treeOff + bl) * NTOK + o2 + i];
    }
    __syncthreads();

    const int sPos = p0 + wv * 16;
    const bool stBin = (sPos < B16);
    const bool alive = (sPos < T);
    const bool hasBin = (p0 < B16);
    const int hiPos = (p0 + 64 < T) ? (p0 + 64) : T;
    const bool hasUn = (hiPos > B16);

    // A-fragments
    bf16x8 ax[4], ah[8];
    {
        int row = wv * 16 + l16;
        int node = nid[row];
        int bl = node >> lvl, i = node - (bl << lvl);
        long crow = (long)bl * (cnt << 1) + 2 * i;
        int tk = tokL[row];
#pragma unroll
        for (int ks = 0; ks < 4; ++ks)
            ax[ks] = ldA(emb, (long)tk * 128 + ks * 32 + quad * 8, isbf);
#pragma unroll
        for (int ks = 0; ks < 8; ++ks) {
            int k0 = ks * 32 + quad * 8;
            int side = k0 >> 7, kl = k0 & 127;
            ah[ks] = *(const bf16x8*)(hChild +
                ((long)(kl >> 4) * Mchild + crow + side) * 16 + (kl & 15));
        }
    }

    for (int jx = 0; jx < JCC; ++jx) {
        const int jc = jcLo + jx;
        const short* wbin = wb + BINW + (long)jc * (56 * 512);
        const short* wun  = wb + UNW  + (long)jc * (16 * 512);
        const int j = jc * 16 + l16;
        const float4 bw = ((const float4*)(bias + BW4))[j];
        const float4 bb = ((const float4*)(bias + BUB4))[j];
        const float  b1 = (bias + BUB1)[j];
        const float4 bu = ((const float4*)(bias + BUU4))[j];

        // c prefetch for this jc
        float clv[4], crv[4];
#pragma unroll
        for (int r = 0; r < 4; ++r) {
            clv[r] = 0.f; crv[r] = 0.f;
            if (!leafchild) {
                int rowe = wv * 16 + quad * 4 + r;
                int node = nid[rowe];
                int bl = node >> lvl, i = node - (bl << lvl);
                long crowe = (long)bl * (cnt << 1) + 2 * i;
                clv[r] = cChild[((long)jc * Mchild + crowe) * 16 + l16];
                if (stBin) crv[r] = cChild[((long)jc * Mchild + crowe + 1) * 16 + l16];
            }
        }

        // bias-folded accumulator init
        f32x4 aW[4], aB[5], aU[4];
        aW[0] = (f32x4){bw.x, bw.x, bw.x, bw.x};
        aW[1] = (f32x4){bw.y, bw.y, bw.y, bw.y};
        aW[2] = (f32x4){bw.z, bw.z, bw.z, bw.z};
        aW[3] = (f32x4){bw.w, bw.w, bw.w, bw.w};
        aB[0] = (f32x4){bb.x, bb.x, bb.x, bb.x};
        aB[1] = (f32x4){bb.y, bb.y, bb.y, bb.y};
        aB[2] = (f32x4){bb.z, bb.z, bb.z, bb.z};
        aB[3] = (f32x4){bb.w, bb.w, bb.w, bb.w};
        aB[4] = (f32x4){b1, b1, b1, b1};
        aU[0] = (f32x4){bu.x, bu.x, bu.x, bu.x};
        aU[1] = (f32x4){bu.y, bu.y, bu.y, bu.y};
        aU[2] = (f32x4){bu.z, bu.z, bu.z, bu.z};
        aU[3] = (f32x4){bu.w, bu.w, bu.w, bu.w};

        if (hasBin) {
            stageF(wbin, Bs, t, 32);
            __syncthreads();
            if (alive) {
#pragma unroll
                for (int f = 0; f < 16; ++f) {
                    bf16x8 b = *(const bf16x8*)&Bs[f * 512 + lane * 8];
                    aW[f >> 2] = MFMA(ax[f & 3], b, aW[f >> 2]);
                }
            }
            if (stBin) {
#pragma unroll
                for (int f = 16; f < 32; ++f) {
                    bf16x8 b = *(const bf16x8*)&Bs[f * 512 + lane * 8];
                    int fb = f - 16;
                    aB[fb >> 3] = MFMA(ah[fb & 7], b, aB[fb >> 3]);
                }
            }
            __syncthreads();
            stageF(wbin + 32 * 512, Bs, t, 24);
            __syncthreads();
            if (stBin) {
#pragma unroll
                for (int f = 0; f < 24; ++f) {
                    bf16x8 b = *(const bf16x8*)&Bs[f * 512 + lane * 8];
                    int fb = f + 16;
                    aB[fb >> 3] = MFMA(ah[fb & 7], b, aB[fb >> 3]);
                }
            }
            if (hasUn) {
                __syncthreads();
                stageF(wun, Bs, t, 16);
                __syncthreads();
                if (alive && !stBin) {
#pragma unroll
                    for (int f = 0; f < 16; ++f) {
                        bf16x8 b = *(const bf16x8*)&Bs[f * 512 + lane * 8];
                        aU[f >> 2] = MFMA(ah[f & 3], b, aU[f >> 2]);
                    }
                }
            }
        } else {
            stageF(wbin, Bs, t, 16);
            stageF(wun, Bs + 16 * 512, t, 16);
            __syncthreads();
            if (alive) {
#pragma unroll
                for (int f = 0; f < 16; ++f) {
                    bf16x8 b = *(const bf16x8*)&Bs[f * 512 + lane * 8];
                    aW[f >> 2] = MFMA(ax[f & 3], b, aW[f >> 2]);
                }
#pragma unroll
                for (int f = 16; f < 32; ++f) {
                    bf16x8 b = *(const bf16x8*)&Bs[f * 512 + lane * 8];
                    aU[(f - 16) >> 2] = MFMA(ah[(f - 16) & 3], b, aU[(f - 16) >> 2]);
                }
            }
        }

        // ---- epilogue (type uniform per wave subtile) ----
        if (alive) {
#pragma unroll
            for (int r = 0; r < 4; ++r) {
                int rowe = wv * 16 + quad * 4 + r;
                int node = nid[rowe];
                int bl = node >> lvl;
                float pi, pf, po, pu, frv = 0.f, cr = 0.f;
                if (stBin) {
                    pi = aW[0][r] + aB[0][r];
                    pf = aW[1][r] + aB[1][r];
                    po = aW[2][r] + aB[3][r];
                    pu = aW[3][r] + aB[4][r];
                    frv = sigm(aW[1][r] + aB[2][r]);
                    cr = crv[r];
                } else {
                    pi = aW[0][r] + aU[0][r];
                    pf = aW[1][r] + aU[1][r];
                    po = aW[2][r] + aU[2][r];
                    pu = aW[3][r] + aU[3][r];
                }
                float ig = sigm(pi), fg = sigm(pf), og = sigm(po), ug = tanh_(pu);
                float c = ig * ug + fg * clv[r] + frv * cr;
                float h = og * tanh_(c);
                if (isRoot) {
                    rootH[(long)(treeOff + bl) * 128 + j] = h;
                    rootC[(long)(treeOff + bl) * 128 + j] = c;
                } else {
                    cOut[((long)jc * Mtot + node) * 16 + l16] = c;
                    hst[wv][quad * 4 + r][l16] = f2s(h);
                }
            }
        }
        if (!isRoot && alive) {
            int nloc = lane >> 2, c0 = (lane & 3) * 4;
            int roww = wv * 16 + nloc;
            int node = nid[roww];
            uint2 v = *(const uint2*)&hst[wv][nloc][c0];
            *(uint2*)&hOut[((long)jc * Mtot + node) * 16 + c0] = v;
        }
        __syncthreads();   // Bs reuse guard for next jc
    }
}

// ---- output: rootH/rootC fp32 -> d_out ----
__global__ __launch_bounds__(256) void out_kernel(const float* ws, void* out)
{
    const int isbf = ((const int*)ws)[0];
    const float* rootH = ws + OFF_ROOT;
    const float* rootC = rootH + 32768;
    int t = blockIdx.x * 256 + threadIdx.x;
    float h = rootH[t], c = rootC[t];
    if (isbf) {
        ((__hip_bfloat16*)out)[t]         = __float2bfloat16(h);
        ((__hip_bfloat16*)out)[32768 + t] = __float2bfloat16(c);
    } else {
        ((float*)out)[t]         = h;
        ((float*)out)[32768 + t] = c;
    }
}

extern "C" void kernel_launch(void* const* d_in, const int* in_sizes, int n_in,
                              void* d_out, int out_size, void* d_ws, size_t ws_size,
                              hipStream_t stream)
{
    const int* tokens = (const int*)d_in[0];
    const int* arity  = (const int*)d_in[1];
    const void* emb   = d_in[2];
    const void* W     = d_in[3];
    const void* bW    = d_in[4];
    const void* Ubin  = d_in[5];
    const void* bUbin = d_in[6];
    const void* Uun   = d_in[7];
    const void* bUun  = d_in[8];

    float* ws = (float*)d_ws;
    int* ws_i = (int*)d_ws;

    int Bc = 256;
    while (Bc > 1 && (size_t)(OFF_CHUNK + Bc * PER_TREE) * 4 > ws_size) Bc >>= 1;
    const int nCh = 256 / Bc;
    int bcsh = 0; while ((1 << bcsh) < Bc) ++bcsh;
    const int lstride = 255 * Bc + 512;
    const int nPairs = nCh * 8;
    int nSegMax = (Bc << 7) >> 8; if (nSegMax < 1) nSegMax = 1;

    detect_kernel<<<1, 64, 0, stream>>>(W, ws);
    repack_mfma<<<128, 256, 0, stream>>>(W, bW, Ubin, bUbin, Uun, bUun, ws);
    {
        dim3 pg(nSegMax, nPairs);
        count_seg<<<pg, 256, 0, stream>>>(arity, ws_i, bcsh, Bc, nSegMax);
        prefix_kernel<<<1, 256, 0, stream>>>(ws_i, nPairs, Bc, nSegMax);
        scatter_seg<<<pg, 256, 0, stream>>>(arity, ws_i, bcsh, Bc, nSegMax, lstride);
        pad_kernel<<<1, 256, 0, stream>>>(ws_i, nPairs, Bc, lstride);
    }

    short* Ha = (short*)(ws + OFF_CHUNK);
    short* Hb = Ha + (long)Bc * 32768;
    float* Ca = (float*)(Hb + (long)Bc * 16384);
    float* Cb = Ca + (long)Bc * 8192;
    float* rootH = ws + OFF_ROOT;
    float* rootC = rootH + 32768;

    for (int cidx = 0; cidx < nCh; ++cidx) {
        int toff = cidx * Bc;
        {
            int Mleaf = Bc * 256;
            int NBL = (Mleaf + 63) / 64; if (NBL > 512) NBL = 512;
            int itersL = (Mleaf + NBL * 64 - 1) / (NBL * 64);
            leaf_mfma<<<NBL, 256, 0, stream>>>(tokens, emb, ws, Ha, toff, Mleaf, itersL);
        }
        for (int l = 7; l >= 0; --l) {
            int M = Bc << l;
            int Mchild = Bc << (l + 1);
            int nb = (M + 32 + 63) / 64;
            int js = 1;
            while (js < 8 && nb * js < 1024) js <<= 1;
            int jcc = 8 / js;
            const short* hC = (l & 1) ? Ha : Hb;
            const float* cC = (l & 1) ? Ca : Cb;
            short* hO = (l & 1) ? Hb : Ha;
            float* cO = (l & 1) ? Cb : Ca;
            int lc = (l == 7) ? 1 : 0;
            int isRoot = (l == 0) ? 1 : 0;
            int hdrIdx = cidx * 8 + l;
            int lbase = cidx * lstride + Bc * ((1 << l) - 1) + 64 * l;
            dim3 grid(nb * js);
            if (jcc == 8)
                level_mfma<8><<<grid, 256, 0, stream>>>(tokens, emb, ws, hC, cC, hO, cO,
                    rootH, rootC, l, toff, lc, isRoot, M, Mchild, nb, hdrIdx, lbase);
            else if (jcc == 4)
                level_mfma<4><<<grid, 256, 0, stream>>>(tokens, emb, ws, hC, cC, hO, cO,
                    rootH, rootC, l, toff, lc, isRoot, M, Mchild, nb, hdrIdx, lbase);
            else if (jcc == 2)
                level_mfma<2><<<grid, 256, 0, stream>>>(tokens, emb, ws, hC, cC, hO, cO,
                    rootH, rootC, l, toff, lc, isRoot, M, Mchild, nb, hdrIdx, lbase);
            else
                level_mfma<1><<<grid, 256, 0, stream>>>(tokens, emb, ws, hC, cC, hO, cO,
                    rootH, rootC, l, toff, lc, isRoot, M, Mchild, nb, hdrIdx, lbase);
        }
    }
    out_kernel<<<128, 256, 0, stream>>>(ws, d_out);
}